// Round 6
// baseline (742.982 us; speedup 1.0000x reference)
//
#include <hip/hip_runtime.h>
#include <math.h>

#define B_  128
#define P_  2048
#define NB_ 2000
#define NF_ 250
#define NC_ 16
#define R_  128
#define LS_ 1750   // NB-NF (len_sim)
#define NT_ 1751   // NB-NF+1
#define BR_ (B_ * R_)
#define H_  16     // steps per block

typedef int v4i __attribute__((ext_vector_type(4)));

// ---- DPP quad-perm on f64 (2x mov_dpp b32) ----
template <int CTRL>
__device__ __forceinline__ double dpp64(double v) {
    long long x = __double_as_longlong(v);
    int lo = (int)x, hi = (int)(x >> 32);
    lo = __builtin_amdgcn_mov_dpp(lo, CTRL, 0xF, 0xF, true);
    hi = __builtin_amdgcn_mov_dpp(hi, CTRL, 0xF, 0xF, true);
    return __longlong_as_double(((long long)(unsigned)lo) | ((long long)hi << 32));
}
// xor1 = 0xB1, xor2 = 0x4E, bcast s = s*0x55

__device__ __forceinline__ double lu_of(float uf) {
    double u = (double)uf;
    return log(u / (1.0 - u));
}

// ---------------- fused: ft (blocks 0..6) + sdot (blocks 7..134) ----------------
__global__ __launch_bounds__(256) void k_pre(const float* __restrict__ st,
                                             const float* __restrict__ stf,
                                             const float* __restrict__ sp,
                                             const float* __restrict__ sf,
                                             double* __restrict__ ft,
                                             double* __restrict__ sdot) {
    if (blockIdx.x < 7) {
        int t = blockIdx.x * 256 + threadIdx.x;
        if (t >= NT_) return;
        double s = 0.0;
        for (int k = 0; k < NF_; ++k) s += (double)st[t + k] * (double)stf[k];
        ft[t] = s;
    } else {
        __shared__ double red[256];
        int b = blockIdx.x - 7;
        double s = 0.0;
        for (int p = threadIdx.x; p < P_; p += 256)
            s += (double)sp[(size_t)b * P_ + p] * (double)sf[p];
        red[threadIdx.x] = s;
        __syncthreads();
        for (int off = 128; off > 0; off >>= 1) {
            if (threadIdx.x < off) red[threadIdx.x] += red[threadIdx.x + off];
            __syncthreads();
        }
        if (threadIdx.x == 0) sdot[b] = red[0];
    }
}

// ---------------- gensig[b,t] = sdot[b]*ft[t] + bias + coup[b,t], f64 ----------------
__global__ __launch_bounds__(256) void k_coup(const float* __restrict__ cc,
                                              const float* __restrict__ cf,
                                              const double* __restrict__ sdot,
                                              const double* __restrict__ ft,
                                              const float* __restrict__ bias,
                                              double* __restrict__ gensig) {
    __shared__ __align__(16) float  ccs[NC_ * 512];   // 32 KB
    __shared__ __align__(16) double cfs[NC_ * 256];   // 32 KB
    __shared__ double red[3][64][4];                  // 6 KB
    int b = blockIdx.y, t0 = blockIdx.x * 256;
    int tid = threadIdx.x, lane = tid & 63, wv = tid >> 6;

    for (int idx = tid; idx < NC_ * 128; idx += 256) {
        int c = idx >> 7, j4 = (idx & 127) * 4, src = t0 + j4;
        const float* p = cc + ((size_t)b * NC_ + c) * NB_ + src;
        float4 v;
        if (src + 3 < NB_) v = *(const float4*)p;
        else {
            v.x = (src     < NB_) ? p[0] : 0.f;
            v.y = (src + 1 < NB_) ? p[1] : 0.f;
            v.z = (src + 2 < NB_) ? p[2] : 0.f;
            v.w = (src + 3 < NB_) ? p[3] : 0.f;
        }
        *(float4*)&ccs[c * 512 + j4] = v;
    }
    for (int idx = tid; idx < NC_ * 256; idx += 256) {
        int c = idx >> 8, k = idx & 255;
        cfs[idx] = (k < NF_) ? (double)cf[c * NF_ + k] : 0.0;
    }
    __syncthreads();

    double a0 = 0, a1 = 0, a2 = 0, a3 = 0;
    int base = lane * 4;
    for (int c = wv; c < NC_; c += 4) {
        const float*  row  = &ccs[c * 512];
        const double* crow = &cfs[c * 256];
        float4 cur = *(const float4*)&row[base];
        for (int k4 = 0; k4 < 252; k4 += 4) {
            float4 nxt = *(const float4*)&row[base + k4 + 4];
            double e0 = cur.x, e1 = cur.y, e2 = cur.z, e3 = cur.w;
            double e4 = nxt.x, e5 = nxt.y, e6 = nxt.z;
            double c0 = crow[k4], c1 = crow[k4 + 1], c2 = crow[k4 + 2], c3 = crow[k4 + 3];
            a0 += e0 * c0 + e1 * c1 + e2 * c2 + e3 * c3;
            a1 += e1 * c0 + e2 * c1 + e3 * c2 + e4 * c3;
            a2 += e2 * c0 + e3 * c1 + e4 * c2 + e5 * c3;
            a3 += e3 * c0 + e4 * c1 + e5 * c2 + e6 * c3;
            cur = nxt;
        }
    }
    if (wv > 0) {
        red[wv - 1][lane][0] = a0; red[wv - 1][lane][1] = a1;
        red[wv - 1][lane][2] = a2; red[wv - 1][lane][3] = a3;
    }
    __syncthreads();
    if (wv == 0) {
        a0 += red[0][lane][0] + red[1][lane][0] + red[2][lane][0];
        a1 += red[0][lane][1] + red[1][lane][1] + red[2][lane][1];
        a2 += red[0][lane][2] + red[1][lane][2] + red[2][lane][2];
        a3 += red[0][lane][3] + red[1][lane][3] + red[2][lane][3];
        double gb = (double)bias[0];
        double sd = sdot[b];
        double accs[4] = {a0, a1, a2, a3};
        int tb = t0 + base;
        for (int i = 0; i < 4; ++i) {
            int t = tb + i;
            if (t < LS_) gensig[(size_t)b * LS_ + t] = sd * ft[t] + gb + accs[i];
        }
    }
}

// ---------------- logit precompute: lu[i] = log(u/(1-u)) in f64 ----------------
__global__ __launch_bounds__(256) void k_lu(const float* __restrict__ u,
                                            double* __restrict__ lu) {
    size_t i = ((size_t)blockIdx.x * 256 + (size_t)threadIdx.x) * 4;
    float4 v = *(const float4*)(u + i);
    double2 o0, o1;
    o0.x = lu_of(v.x); o0.y = lu_of(v.y);
    o1.x = lu_of(v.z); o1.y = lu_of(v.w);
    *(double2*)(lu + i)     = o0;
    *(double2*)(lu + i + 2) = o1;
}

// ---------------- scan: pipelined i8-MFMA far (ages>=33) + 32-age near recursion ----
// wave gw: b = gw>>3, rbase = (gw&7)*16. Lane roles:
//   lw = l&15 : window-chain (A row m) / far C col n (step)
//   q  = l>>4 : MFMA K-quad / C row group
//   cn = l>>2 : near chain; j = l&3 : near sub-lane (ages 8j+1..8j+8)
template <int PRE>
__global__ __launch_bounds__(256, 1) void k_scan(const double* __restrict__ gensig,
                                                 const float* __restrict__ u,
                                                 const double* __restrict__ luws,
                                                 const float* __restrict__ iss,
                                                 const float* __restrict__ ff,
                                                 float* __restrict__ out) {
    __shared__ double farT_all[4][16 * 17];
    int tid = threadIdx.x;
    int wv = tid >> 6, l = tid & 63;
    int gw = blockIdx.x * 4 + wv;
    int b = gw >> 3, rbase = (gw & 7) * 16;
    double* farT = &farT_all[wv][0];

    int lw = l & 15;
    int q  = l >> 4;
    int cn = l >> 2;
    int j  = l & 3;

    // ---- iss -> out[.., 0:250] ----
    const float* issb = iss + b * NF_;
    for (int idx = l; idx < 16 * NF_; idx += 64) {
        int c = idx / NF_, k = idx - c * NF_;
        out[((size_t)(b * R_ + rbase + c)) * NB_ + k] = issb[k];
    }

    // ---- true window W: bit k = spike(t_cur-250+k) ----
    unsigned long long W0 = 0, W1 = 0, W2 = 0, W3 = 0;
    for (int k = 0; k < NF_; ++k) {
        unsigned long long bit = (issb[k] > 0.5f) ? 1ull : 0ull;
        if      (k <  64) W0 |= bit << k;
        else if (k < 128) W1 |= bit << (k - 64);
        else if (k < 192) W2 |= bit << (k - 128);
        else              W3 |= bit << (k - 192);
    }

    // ---- B planes: F[k][n] = ff[k-n] if 0<=k-n<=217 (age>=33), 5 digit planes, 2^40 ----
    int Bword[4][5][4];
#pragma unroll
    for (int kc = 0; kc < 4; ++kc)
#pragma unroll
        for (int p = 0; p < 5; ++p)
#pragma unroll
            for (int w = 0; w < 4; ++w) Bword[kc][p][w] = 0;
#pragma unroll
    for (int kc = 0; kc < 4; ++kc) {
#pragma unroll
        for (int jj = 0; jj < 16; ++jj) {
            int k = kc * 64 + q * 16 + jj;
            int idx = k - lw;
            long long v = 0;
            if (idx >= 0 && idx <= 217)
                v = __double2ll_rn((double)ff[idx] * 1099511627776.0);   // * 2^40
#pragma unroll
            for (int p = 0; p < 5; ++p) {
                int d = (int)((v + 128) & 255) - 128;
                v = (v - (long long)d) >> 8;
                Bword[kc][p][jj >> 2] |= (d & 255) << ((jj & 3) * 8);
            }
        }
    }
    v4i Bf[4][5];
#pragma unroll
    for (int kc = 0; kc < 4; ++kc)
#pragma unroll
        for (int p = 0; p < 5; ++p) {
            v4i t; t.x = Bword[kc][p][0]; t.y = Bword[kc][p][1];
            t.z = Bword[kc][p][2]; t.w = Bword[kc][p][3];
            Bf[kc][p] = t;
        }

    const double* gs  = gensig + (size_t)b * LS_;
    const float*  up  = u    + b * R_ + rbase + cn;
    const double* lup = luws + b * R_ + rbase + cn;
    float*        op  = out + ((size_t)(b * R_ + rbase + cn)) * NB_ + NF_;

    // near taps: lane j covers ages 8j+1..8j+8 -> ff[249-8j] .. ff[242-8j]
    double tp0 = (double)ff[249 - 8 * j];
    double tp1 = (double)ff[248 - 8 * j];
    double tp2 = (double)ff[247 - 8 * j];
    double tp3 = (double)ff[246 - 8 * j];
    double tp4 = (double)ff[245 - 8 * j];
    double tp5 = (double)ff[244 - 8 * j];
    double tp6 = (double)ff[243 - 8 * j];
    double tp7 = (double)ff[242 - 8 * j];

    // qreg bit d = spike(t_cur-1-d); init from iss: bit d = iss[249-d]
    unsigned qreg = __brev((unsigned)(W3 >> 26));

    // far phase: MFMA over A-source chunks S0..S3 (+ combine + farT write)
    auto do_far = [&](unsigned long long S0, unsigned long long S1,
                      unsigned long long S2, unsigned long long S3, double gp) {
        unsigned long long Sarr[4] = {S0, S1, S2, S3};
        v4i acc[5];
#pragma unroll
        for (int p = 0; p < 5; ++p) acc[p] = (v4i){0, 0, 0, 0};
#pragma unroll
        for (int kc = 0; kc < 4; ++kc) {
            unsigned f = (unsigned)((Sarr[kc] >> (q * 16)) & 0xFFFFull);
            v4i av;
            av.x = (int)((((f      ) & 0xFu) * 0x00204081u) & 0x01010101u);
            av.y = (int)((((f >>  4) & 0xFu) * 0x00204081u) & 0x01010101u);
            av.z = (int)((((f >>  8) & 0xFu) * 0x00204081u) & 0x01010101u);
            av.w = (int)((((f >> 12) & 0xFu) * 0x00204081u) & 0x01010101u);
#pragma unroll
            for (int p = 0; p < 5; ++p)
                acc[p] = __builtin_amdgcn_mfma_i32_16x16x64_i8(av, Bf[kc][p], acc[p], 0, 0, 0);
        }
#pragma unroll
        for (int r = 0; r < 4; ++r) {
            int lo = acc[0][r] + 256 * acc[1][r] + 65536 * acc[2][r];
            int hi = acc[3][r] + 256 * acc[4][r];
            double fb = gp + (double)lo * 0x1p-40 + (double)hi * 0x1p-16;
            farT[(q * 4 + r) * 17 + lw] = fb;
        }
    };

    // ---- prologue: farA(0) from unshifted W (spikes <= -18 used only) ----
    do_far(W0, W1, W2, W3, gs[lw]);
    __asm__ volatile("s_waitcnt lgkmcnt(0)" ::: "memory");
    double farv[16];
#pragma unroll
    for (int i = 0; i < 16; ++i) farv[i] = farT[cn * 17 + i];

    double gprep;
    { int tg = 16 + lw; if (tg > LS_ - 1) tg = LS_ - 1; gprep = gs[tg]; }

    double mylu0, mylu1, mylu2, mylu3;
    double nlu0 = 0, nlu1 = 0, nlu2 = 0, nlu3 = 0;
    float  ur0 = 0, ur1 = 0, ur2 = 0, ur3 = 0;
    {
        int t_;
        if (PRE) {
            t_ = 0  + j; mylu0 = lup[(size_t)t_ * BR_];
            t_ = 4  + j; mylu1 = lup[(size_t)t_ * BR_];
            t_ = 8  + j; mylu2 = lup[(size_t)t_ * BR_];
            t_ = 12 + j; mylu3 = lup[(size_t)t_ * BR_];
            t_ = 16 + j; nlu0 = lup[(size_t)t_ * BR_];
            t_ = 20 + j; nlu1 = lup[(size_t)t_ * BR_];
            t_ = 24 + j; nlu2 = lup[(size_t)t_ * BR_];
            t_ = 28 + j; nlu3 = lup[(size_t)t_ * BR_];
        } else {
            t_ = 0  + j; mylu0 = lu_of(up[(size_t)t_ * BR_]);
            t_ = 4  + j; mylu1 = lu_of(up[(size_t)t_ * BR_]);
            t_ = 8  + j; mylu2 = lu_of(up[(size_t)t_ * BR_]);
            t_ = 12 + j; mylu3 = lu_of(up[(size_t)t_ * BR_]);
            t_ = 16 + j; ur0 = up[(size_t)t_ * BR_];
            t_ = 20 + j; ur1 = up[(size_t)t_ * BR_];
            t_ = 24 + j; ur2 = up[(size_t)t_ * BR_];
            t_ = 28 + j; ur3 = up[(size_t)t_ * BR_];
        }
    }

#define NSTEP(i, S, MYLU) { \
    double lu = dpp64<(S) * 0x55>(MYLU); \
    unsigned qb = (qreg >> (8 * j)) & 255u; \
    double s = ((((qb & 1u)  ? tp0 : 0.0) + ((qb & 2u)  ? tp1 : 0.0)) + \
                (((qb & 4u)  ? tp2 : 0.0) + ((qb & 8u)  ? tp3 : 0.0))) + \
               ((((qb & 16u) ? tp4 : 0.0) + ((qb & 32u) ? tp5 : 0.0)) + \
                (((qb & 64u) ? tp6 : 0.0) + ((qb & 128u)? tp7 : 0.0))); \
    s += dpp64<0xB1>(s); \
    s += dpp64<0x4E>(s); \
    bool sp = (farv[i] + s) > lu; \
    qreg = (qreg << 1) | (sp ? 1u : 0u); \
}

    for (int t0 = 0; t0 < LS_; t0 += H_) {
        bool more = (t0 + H_ < LS_);
        if (more) {
            // farA(t0+16) from W>>16 (spikes <= t0-2 used; have through t0-1)
            do_far((W0 >> 16) | (W1 << 48), (W1 >> 16) | (W2 << 48),
                   (W2 >> 16) | (W3 << 48), (W3 >> 16), gprep);
            int tg = t0 + 32 + lw; if (tg > LS_ - 1) tg = LS_ - 1;
            gprep = gs[tg];
        }

        // ---- NEAR: 16 serial steps, ages 1..32 in registers ----
        NSTEP(0,  0, mylu0) NSTEP(1,  1, mylu0) NSTEP(2,  2, mylu0) NSTEP(3,  3, mylu0)
        NSTEP(4,  0, mylu1) NSTEP(5,  1, mylu1) NSTEP(6,  2, mylu1) NSTEP(7,  3, mylu1)
        NSTEP(8,  0, mylu2) NSTEP(9,  1, mylu2) NSTEP(10, 2, mylu2) NSTEP(11, 3, mylu2)
        NSTEP(12, 0, mylu3) NSTEP(13, 1, mylu3) NSTEP(14, 2, mylu3) NSTEP(15, 3, mylu3)

        // ---- store spikes ----
        unsigned q2 = (__brev(qreg) >> 16) & 0xFFFFu;   // bit i = spike(t0+i)
        int rem = LS_ - t0; if (rem > H_) rem = H_;
        int s0 = 4 * j;
        if (s0 + 3 < rem) {
            float4 o;
            o.x = (float)((q2 >> (s0    )) & 1u);
            o.y = (float)((q2 >> (s0 + 1)) & 1u);
            o.z = (float)((q2 >> (s0 + 2)) & 1u);
            o.w = (float)((q2 >> (s0 + 3)) & 1u);
            *(float4*)(op + t0 + s0) = o;
        } else {
#pragma unroll
            for (int e = 0; e < 4; ++e)
                if (s0 + e < rem) op[t0 + s0 + e] = (float)((q2 >> (s0 + e)) & 1u);
        }

        if (more) {
            // broadcast chain lw's q2 to window owners; advance true W by 16
            int q2i = __builtin_amdgcn_ds_bpermute(lw << 4, (int)q2);
            unsigned long long q2n = (unsigned long long)(unsigned)q2i;
            W0 = (W0 >> 16) | (W1 << 48);
            W1 = (W1 >> 16) | (W2 << 48);
            W2 = (W2 >> 16) | (W3 << 48);
            W3 = (W3 >> 16) | (q2n << 42);
            __asm__ volatile("s_waitcnt lgkmcnt(0)" ::: "memory");
#pragma unroll
            for (int i = 0; i < 16; ++i) farv[i] = farT[cn * 17 + i];

            int t_;
            if (PRE) {
                mylu0 = nlu0; mylu1 = nlu1; mylu2 = nlu2; mylu3 = nlu3;
                t_ = t0 + 32 +  0 + j; if (t_ > LS_ - 1) t_ = LS_ - 1; nlu0 = lup[(size_t)t_ * BR_];
                t_ = t0 + 32 +  4 + j; if (t_ > LS_ - 1) t_ = LS_ - 1; nlu1 = lup[(size_t)t_ * BR_];
                t_ = t0 + 32 +  8 + j; if (t_ > LS_ - 1) t_ = LS_ - 1; nlu2 = lup[(size_t)t_ * BR_];
                t_ = t0 + 32 + 12 + j; if (t_ > LS_ - 1) t_ = LS_ - 1; nlu3 = lup[(size_t)t_ * BR_];
            } else {
                mylu0 = lu_of(ur0); mylu1 = lu_of(ur1);
                mylu2 = lu_of(ur2); mylu3 = lu_of(ur3);
                t_ = t0 + 32 +  0 + j; if (t_ > LS_ - 1) t_ = LS_ - 1; ur0 = up[(size_t)t_ * BR_];
                t_ = t0 + 32 +  4 + j; if (t_ > LS_ - 1) t_ = LS_ - 1; ur1 = up[(size_t)t_ * BR_];
                t_ = t0 + 32 +  8 + j; if (t_ > LS_ - 1) t_ = LS_ - 1; ur2 = up[(size_t)t_ * BR_];
                t_ = t0 + 32 + 12 + j; if (t_ > LS_ - 1) t_ = LS_ - 1; ur3 = up[(size_t)t_ * BR_];
            }
        }
    }
#undef NSTEP
}

extern "C" void kernel_launch(void* const* d_in, const int* in_sizes, int n_in,
                              void* d_out, int out_size, void* d_ws, size_t ws_size,
                              hipStream_t stream) {
    const float* stim_spat = (const float*)d_in[0];   // (128,2048)
    const float* stim_time = (const float*)d_in[1];   // (2000,)
    const float* iss       = (const float*)d_in[2];   // (128,250)
    const float* cc        = (const float*)d_in[3];   // (128,16,2000)
    const float* sf        = (const float*)d_in[4];   // (2048,)
    const float* bias      = (const float*)d_in[5];   // (1,)
    const float* stf       = (const float*)d_in[6];   // (250,)
    const float* ff        = (const float*)d_in[7];   // (250,)
    const float* cf        = (const float*)d_in[8];   // (16,250)
    const float* u         = (const float*)d_in[9];   // (1750,128,128)
    (void)in_sizes; (void)n_in; (void)out_size;

    float* out = (float*)d_out;                       // (128,128,2000)

    double* ws     = (double*)d_ws;
    double* gensig = ws;                              // 224000 f64
    double* ft     = gensig + (size_t)B_ * LS_;       // 1751 f64
    double* sdot   = ft + NT_;                        // 128 f64
    const size_t lu_off = 225880;                     // 16B-aligned
    double* lu_ws  = ws + lu_off;                     // 28,672,000 f64
    size_t need = (lu_off + (size_t)LS_ * BR_) * sizeof(double);
    bool pre = (ws_size >= need);

    k_pre  <<<135, 256, 0, stream>>>(stim_time, stf, stim_spat, sf, ft, sdot);
    k_coup <<<dim3(7, B_), 256, 0, stream>>>(cc, cf, sdot, ft, bias, gensig);
    if (pre) {
        k_lu   <<<(LS_ * BR_) / 1024, 256, 0, stream>>>(u, lu_ws);
        k_scan<1><<<B_ * 2, 256, 0, stream>>>(gensig, u, lu_ws, iss, ff, out);
    } else {
        k_scan<0><<<B_ * 2, 256, 0, stream>>>(gensig, u, lu_ws, iss, ff, out);
    }
}

// Round 7
// 553.029 us; speedup vs baseline: 1.3435x; 1.3435x over previous
//
#include <hip/hip_runtime.h>
#include <math.h>

#define B_  128
#define P_  2048
#define NB_ 2000
#define NF_ 250
#define NC_ 16
#define R_  128
#define LS_ 1750   // NB-NF (len_sim)
#define NT_ 1751   // NB-NF+1
#define BR_ (B_ * R_)
#define H_  16     // steps per block

typedef int v4i __attribute__((ext_vector_type(4)));

// ---- DPP quad-perm on 64-bit (2x mov_dpp b32) ----
template <int CTRL>
__device__ __forceinline__ long long dpp64i(long long x) {
    int lo = (int)x, hi = (int)(x >> 32);
    lo = __builtin_amdgcn_mov_dpp(lo, CTRL, 0xF, 0xF, true);
    hi = __builtin_amdgcn_mov_dpp(hi, CTRL, 0xF, 0xF, true);
    return ((long long)(unsigned)lo) | ((long long)hi << 32);
}
// xor1 = 0xB1, xor2 = 0x4E, bcast s = s*0x55

// ---- custom logit: log(u/(1-u)) f64, abs err < 1e-13 (margin ~2e-7) ----
__device__ __forceinline__ double logit_fast(float uf) {
    double u = (double)uf;
    double v = 1.0 - u;                  // exact (u has 24-bit mantissa)
    double qd = u / v;
    long long bits = __double_as_longlong(qd);
    int e = (int)((bits >> 52) & 0x7FF) - 1023;
    double m = __longlong_as_double((bits & 0xFFFFFFFFFFFFFLL) | 0x3FF0000000000000LL);
    if (m > 1.4142135623730951) { m *= 0.5; e += 1; }   // m in [0.707,1.414]
    double s = (m - 1.0) / (m + 1.0);                   // |s| <= 0.1716
    double z = s * s;
    double Q = fma(z, fma(z, fma(z, fma(z, fma(z, fma(z,
        0.06666666666666667, 0.07692307692307693), 0.09090909090909091),
        0.1111111111111111), 0.14285714285714285), 0.2), 0.3333333333333333);
    double logm = fma(2.0 * s, z * Q, 2.0 * s);         // 2*atanh(s)
    return fma((double)e, 0.6931471805599453, logm);
}

// ---- clamp + quantize threshold to i64 at 2^45 (|ns| < 8 guaranteed) ----
__device__ __forceinline__ long long thrq_of(double lu, double fb) {
    double thr = lu - fb;
    thr = fmin(fmax(thr, -8.0), 8.0);
    double d = fma(thr, 0x1p45, 0x1.8p52);              // + (2^52 + 2^51)
    return (__double_as_longlong(d) & 0xFFFFFFFFFFFFFLL) - (1LL << 51);
}

// ---------------- fused: ft (blocks 0..6) + sdot (blocks 7..134) ----------------
__global__ __launch_bounds__(256) void k_pre(const float* __restrict__ st,
                                             const float* __restrict__ stf,
                                             const float* __restrict__ sp,
                                             const float* __restrict__ sf,
                                             double* __restrict__ ft,
                                             double* __restrict__ sdot) {
    if (blockIdx.x < 7) {
        int t = blockIdx.x * 256 + threadIdx.x;
        if (t >= NT_) return;
        double s = 0.0;
        for (int k = 0; k < NF_; ++k) s += (double)st[t + k] * (double)stf[k];
        ft[t] = s;
    } else {
        __shared__ double red[256];
        int b = blockIdx.x - 7;
        double s = 0.0;
        for (int p = threadIdx.x; p < P_; p += 256)
            s += (double)sp[(size_t)b * P_ + p] * (double)sf[p];
        red[threadIdx.x] = s;
        __syncthreads();
        for (int off = 128; off > 0; off >>= 1) {
            if (threadIdx.x < off) red[threadIdx.x] += red[threadIdx.x + off];
            __syncthreads();
        }
        if (threadIdx.x == 0) sdot[b] = red[0];
    }
}

// ---------------- gensig[b,t] = sdot[b]*ft[t] + bias + coup[b,t], f64 ----------------
__global__ __launch_bounds__(256) void k_coup(const float* __restrict__ cc,
                                              const float* __restrict__ cf,
                                              const double* __restrict__ sdot,
                                              const double* __restrict__ ft,
                                              const float* __restrict__ bias,
                                              double* __restrict__ gensig) {
    __shared__ __align__(16) float  ccs[NC_ * 512];   // 32 KB
    __shared__ __align__(16) double cfs[NC_ * 256];   // 32 KB
    __shared__ double red[3][64][4];                  // 6 KB
    int b = blockIdx.y, t0 = blockIdx.x * 256;
    int tid = threadIdx.x, lane = tid & 63, wv = tid >> 6;

    for (int idx = tid; idx < NC_ * 128; idx += 256) {
        int c = idx >> 7, j4 = (idx & 127) * 4, src = t0 + j4;
        const float* p = cc + ((size_t)b * NC_ + c) * NB_ + src;
        float4 v;
        if (src + 3 < NB_) v = *(const float4*)p;
        else {
            v.x = (src     < NB_) ? p[0] : 0.f;
            v.y = (src + 1 < NB_) ? p[1] : 0.f;
            v.z = (src + 2 < NB_) ? p[2] : 0.f;
            v.w = (src + 3 < NB_) ? p[3] : 0.f;
        }
        *(float4*)&ccs[c * 512 + j4] = v;
    }
    for (int idx = tid; idx < NC_ * 256; idx += 256) {
        int c = idx >> 8, k = idx & 255;
        cfs[idx] = (k < NF_) ? (double)cf[c * NF_ + k] : 0.0;
    }
    __syncthreads();

    double a0 = 0, a1 = 0, a2 = 0, a3 = 0;
    int base = lane * 4;
    for (int c = wv; c < NC_; c += 4) {
        const float*  row  = &ccs[c * 512];
        const double* crow = &cfs[c * 256];
        float4 cur = *(const float4*)&row[base];
        for (int k4 = 0; k4 < 252; k4 += 4) {
            float4 nxt = *(const float4*)&row[base + k4 + 4];
            double e0 = cur.x, e1 = cur.y, e2 = cur.z, e3 = cur.w;
            double e4 = nxt.x, e5 = nxt.y, e6 = nxt.z;
            double c0 = crow[k4], c1 = crow[k4 + 1], c2 = crow[k4 + 2], c3 = crow[k4 + 3];
            a0 += e0 * c0 + e1 * c1 + e2 * c2 + e3 * c3;
            a1 += e1 * c0 + e2 * c1 + e3 * c2 + e4 * c3;
            a2 += e2 * c0 + e3 * c1 + e4 * c2 + e5 * c3;
            a3 += e3 * c0 + e4 * c1 + e5 * c2 + e6 * c3;
            cur = nxt;
        }
    }
    if (wv > 0) {
        red[wv - 1][lane][0] = a0; red[wv - 1][lane][1] = a1;
        red[wv - 1][lane][2] = a2; red[wv - 1][lane][3] = a3;
    }
    __syncthreads();
    if (wv == 0) {
        a0 += red[0][lane][0] + red[1][lane][0] + red[2][lane][0];
        a1 += red[0][lane][1] + red[1][lane][1] + red[2][lane][1];
        a2 += red[0][lane][2] + red[1][lane][2] + red[2][lane][2];
        a3 += red[0][lane][3] + red[1][lane][3] + red[2][lane][3];
        double gb = (double)bias[0];
        double sd = sdot[b];
        double accs[4] = {a0, a1, a2, a3};
        int tb = t0 + base;
        for (int i = 0; i < 4; ++i) {
            int t = tb + i;
            if (t < LS_) gensig[(size_t)b * LS_ + t] = sd * ft[t] + gb + accs[i];
        }
    }
}

// ---------------- scan: i8-MFMA far (f64 fb) + i64 near recursion w/ precomputed thr ----
// wave gw: b = gw>>3, rbase = (gw&7)*16. Lane roles:
//   lw = l&15 : window-chain (A row) / far step col n
//   q  = l>>4 : MFMA K-quad; far-combine chain = q*4+r
//   cn = l>>2 : near chain; j = l&3 : near sub-lane (ages 4j+1..4j+4; steps 4a+j logits)
__global__ __launch_bounds__(256, 1) void k_scan(const double* __restrict__ gensig,
                                                 const float* __restrict__ u,
                                                 const float* __restrict__ iss,
                                                 const float* __restrict__ ff,
                                                 float* __restrict__ out) {
    __shared__ double farT_all[4][16 * 17];
    int tid = threadIdx.x;
    int wv = tid >> 6, l = tid & 63;
    int gw = blockIdx.x * 4 + wv;
    int b = gw >> 3, rbase = (gw & 7) * 16;
    double* farT = &farT_all[wv][0];

    int lw = l & 15;
    int q  = l >> 4;
    int cn = l >> 2;
    int j  = l & 3;

    // ---- iss -> out[.., 0:250] ----
    const float* issb = iss + b * NF_;
    for (int idx = l; idx < 16 * NF_; idx += 64) {
        int c = idx / NF_, k = idx - c * NF_;
        out[((size_t)(b * R_ + rbase + c)) * NB_ + k] = issb[k];
    }

    // ---- window: bit k = spike(t0-250+k); identical across chains initially ----
    unsigned long long W0 = 0, W1 = 0, W2 = 0, W3 = 0;
    for (int k = 0; k < NF_; ++k) {
        unsigned long long bit = (issb[k] > 0.5f) ? 1ull : 0ull;
        if      (k <  64) W0 |= bit << k;
        else if (k < 128) W1 |= bit << (k - 64);
        else if (k < 192) W2 |= bit << (k - 128);
        else              W3 |= bit << (k - 192);
    }

    // ---- B: F[k][n] = ff[k-n], 0<=k-n<=249; 6 signed base-256 digit planes @2^48 ----
    int Bword[4][6][4];
#pragma unroll
    for (int kc = 0; kc < 4; ++kc)
#pragma unroll
        for (int p = 0; p < 6; ++p)
#pragma unroll
            for (int w = 0; w < 4; ++w) Bword[kc][p][w] = 0;
#pragma unroll
    for (int kc = 0; kc < 4; ++kc) {
#pragma unroll
        for (int jj = 0; jj < 16; ++jj) {
            int k = kc * 64 + q * 16 + jj;
            int idx = k - lw;
            long long v = 0;
            if (idx >= 0 && idx < NF_)
                v = __double2ll_rn((double)ff[idx] * 281474976710656.0);   // * 2^48
#pragma unroll
            for (int p = 0; p < 6; ++p) {
                int d = (int)((v + 128) & 255) - 128;
                v = (v - (long long)d) >> 8;
                Bword[kc][p][jj >> 2] |= (d & 255) << ((jj & 3) * 8);
            }
        }
    }
    v4i Bf[4][6];
#pragma unroll
    for (int kc = 0; kc < 4; ++kc)
#pragma unroll
        for (int p = 0; p < 6; ++p) {
            v4i t; t.x = Bword[kc][p][0]; t.y = Bword[kc][p][1];
            t.z = Bword[kc][p][2]; t.w = Bword[kc][p][3];
            Bf[kc][p] = t;
        }

    const double* gs = gensig + (size_t)b * LS_;
    const float*  up = u + b * R_ + rbase + cn;
    float*        op = out + ((size_t)(b * R_ + rbase + cn)) * NB_ + NF_;

    // near taps in i64 @2^45: lane j covers ages 4j+1..4j+4
    long long tq0 = __double2ll_rn((double)ff[249 - 4 * j] * 0x1p45);
    long long tq1 = __double2ll_rn((double)ff[248 - 4 * j] * 0x1p45);
    long long tq2 = __double2ll_rn((double)ff[247 - 4 * j] * 0x1p45);
    long long tq3 = __double2ll_rn((double)ff[246 - 4 * j] * 0x1p45);

    // far phase: fb[chain=q*4+r][step=lw] = gp + sum_k W[k]*ff[k-lw]
    auto do_far = [&](double gp) {
        unsigned long long Sarr[4] = {W0, W1, W2, W3};
        v4i acc[6];
#pragma unroll
        for (int p = 0; p < 6; ++p) acc[p] = (v4i){0, 0, 0, 0};
#pragma unroll
        for (int kc = 0; kc < 4; ++kc) {
            unsigned f = (unsigned)((Sarr[kc] >> (q * 16)) & 0xFFFFull);
            v4i av;
            av.x = (int)((((f      ) & 0xFu) * 0x00204081u) & 0x01010101u);
            av.y = (int)((((f >>  4) & 0xFu) * 0x00204081u) & 0x01010101u);
            av.z = (int)((((f >>  8) & 0xFu) * 0x00204081u) & 0x01010101u);
            av.w = (int)((((f >> 12) & 0xFu) * 0x00204081u) & 0x01010101u);
#pragma unroll
            for (int p = 0; p < 6; ++p)
                acc[p] = __builtin_amdgcn_mfma_i32_16x16x64_i8(av, Bf[kc][p], acc[p], 0, 0, 0);
        }
#pragma unroll
        for (int r = 0; r < 4; ++r) {
            int lo = acc[0][r] + acc[1][r] * 256 + acc[2][r] * 65536;
            int hi = acc[3][r] + acc[4][r] * 256 + acc[5][r] * 65536;
            double fb = gp + (double)lo * 0x1p-48 + (double)hi * 0x1p-24;
            farT[(q * 4 + r) * 17 + lw] = fb;
        }
    };

    // ---- prologue: block 0 ----
    double gprep = gs[lw];
    float ur0, ur1, ur2, ur3;
    {
        int t_;
        t_ = 0  + j; ur0 = up[(size_t)t_ * BR_];
        t_ = 4  + j; ur1 = up[(size_t)t_ * BR_];
        t_ = 8  + j; ur2 = up[(size_t)t_ * BR_];
        t_ = 12 + j; ur3 = up[(size_t)t_ * BR_];
    }
    long long thrq0, thrq1, thrq2, thrq3;
    do_far(gprep);
    {
        double lu0 = logit_fast(ur0), lu1 = logit_fast(ur1);
        double lu2 = logit_fast(ur2), lu3 = logit_fast(ur3);
        __asm__ volatile("s_waitcnt lgkmcnt(0)" ::: "memory");
        thrq0 = thrq_of(lu0, farT[cn * 17 + j]);
        thrq1 = thrq_of(lu1, farT[cn * 17 + 4 + j]);
        thrq2 = thrq_of(lu2, farT[cn * 17 + 8 + j]);
        thrq3 = thrq_of(lu3, farT[cn * 17 + 12 + j]);
    }
    { int tg = 16 + lw; if (tg > LS_ - 1) tg = LS_ - 1; gprep = gs[tg]; }
    {
        int t_;
        t_ = 16 + j;      if (t_ > LS_ - 1) t_ = LS_ - 1; ur0 = up[(size_t)t_ * BR_];
        t_ = 20 + j;      if (t_ > LS_ - 1) t_ = LS_ - 1; ur1 = up[(size_t)t_ * BR_];
        t_ = 24 + j;      if (t_ > LS_ - 1) t_ = LS_ - 1; ur2 = up[(size_t)t_ * BR_];
        t_ = 28 + j;      if (t_ > LS_ - 1) t_ = LS_ - 1; ur3 = up[(size_t)t_ * BR_];
    }

#define NSTEP(S, THRQ) { \
    long long thr = dpp64i<(S) * 0x55>(THRQ); \
    unsigned qb = (qreg >> (4 * j)) & 15u; \
    long long s = (((qb & 1u) ? tq0 : 0LL) + ((qb & 2u) ? tq1 : 0LL)) \
                + (((qb & 4u) ? tq2 : 0LL) + ((qb & 8u) ? tq3 : 0LL)); \
    s += dpp64i<0xB1>(s); \
    s += dpp64i<0x4E>(s); \
    bool sp = s > thr; \
    qreg = (qreg << 1) | (sp ? 1u : 0u); \
}

    for (int t0 = 0; t0 < LS_; t0 += H_) {
        // ---- NEAR: 16 serial steps, pure i64 + DPP ----
        unsigned qreg = 0;
        NSTEP(0, thrq0) NSTEP(1, thrq0) NSTEP(2, thrq0) NSTEP(3, thrq0)
        NSTEP(0, thrq1) NSTEP(1, thrq1) NSTEP(2, thrq1) NSTEP(3, thrq1)
        NSTEP(0, thrq2) NSTEP(1, thrq2) NSTEP(2, thrq2) NSTEP(3, thrq2)
        NSTEP(0, thrq3) NSTEP(1, thrq3) NSTEP(2, thrq3) NSTEP(3, thrq3)

        // ---- store spikes ----
        unsigned q2 = (__brev(qreg) >> 16) & 0xFFFFu;   // bit i = spike(t0+i)
        int rem = LS_ - t0; if (rem > H_) rem = H_;
        int s0 = 4 * j;
        if (s0 + 3 < rem) {
            float4 o;
            o.x = (float)((q2 >> (s0    )) & 1u);
            o.y = (float)((q2 >> (s0 + 1)) & 1u);
            o.z = (float)((q2 >> (s0 + 2)) & 1u);
            o.w = (float)((q2 >> (s0 + 3)) & 1u);
            *(float4*)(op + t0 + s0) = o;
        } else {
#pragma unroll
            for (int e = 0; e < 4; ++e)
                if (s0 + e < rem) op[t0 + s0 + e] = (float)((q2 >> (s0 + e)) & 1u);
        }

        if (t0 + H_ < LS_) {
            // advance per-chain window with chain lw's new spikes
            int q2i = __builtin_amdgcn_ds_bpermute(lw << 4, (int)q2);
            unsigned long long q2n = (unsigned long long)(unsigned)q2i;
            W0 = (W0 >> 16) | (W1 << 48);
            W1 = (W1 >> 16) | (W2 << 48);
            W2 = (W2 >> 16) | (W3 << 48);
            W3 = (W3 >> 16) | (q2n << 42);

            do_far(gprep);                                  // block t0+16
            // logits for block t0+16 issue while MFMAs execute
            double lu0 = logit_fast(ur0), lu1 = logit_fast(ur1);
            double lu2 = logit_fast(ur2), lu3 = logit_fast(ur3);
            __asm__ volatile("s_waitcnt lgkmcnt(0)" ::: "memory");
            thrq0 = thrq_of(lu0, farT[cn * 17 + j]);
            thrq1 = thrq_of(lu1, farT[cn * 17 + 4 + j]);
            thrq2 = thrq_of(lu2, farT[cn * 17 + 8 + j]);
            thrq3 = thrq_of(lu3, farT[cn * 17 + 12 + j]);

            int tg = t0 + 32 + lw; if (tg > LS_ - 1) tg = LS_ - 1;
            gprep = gs[tg];
            int t_;
            t_ = t0 + 32 +  0 + j; if (t_ > LS_ - 1) t_ = LS_ - 1; ur0 = up[(size_t)t_ * BR_];
            t_ = t0 + 32 +  4 + j; if (t_ > LS_ - 1) t_ = LS_ - 1; ur1 = up[(size_t)t_ * BR_];
            t_ = t0 + 32 +  8 + j; if (t_ > LS_ - 1) t_ = LS_ - 1; ur2 = up[(size_t)t_ * BR_];
            t_ = t0 + 32 + 12 + j; if (t_ > LS_ - 1) t_ = LS_ - 1; ur3 = up[(size_t)t_ * BR_];
        }
    }
#undef NSTEP
}

extern "C" void kernel_launch(void* const* d_in, const int* in_sizes, int n_in,
                              void* d_out, int out_size, void* d_ws, size_t ws_size,
                              hipStream_t stream) {
    const float* stim_spat = (const float*)d_in[0];   // (128,2048)
    const float* stim_time = (const float*)d_in[1];   // (2000,)
    const float* iss       = (const float*)d_in[2];   // (128,250)
    const float* cc        = (const float*)d_in[3];   // (128,16,2000)
    const float* sf        = (const float*)d_in[4];   // (2048,)
    const float* bias      = (const float*)d_in[5];   // (1,)
    const float* stf       = (const float*)d_in[6];   // (250,)
    const float* ff        = (const float*)d_in[7];   // (250,)
    const float* cf        = (const float*)d_in[8];   // (16,250)
    const float* u         = (const float*)d_in[9];   // (1750,128,128)
    (void)in_sizes; (void)n_in; (void)out_size; (void)ws_size;

    float* out = (float*)d_out;                       // (128,128,2000)

    double* ws     = (double*)d_ws;
    double* gensig = ws;                              // 128*1750 f64
    double* ft     = gensig + (size_t)B_ * LS_;       // 1751 f64
    double* sdot   = ft + NT_;                        // 128 f64

    k_pre  <<<135, 256, 0, stream>>>(stim_time, stf, stim_spat, sf, ft, sdot);
    k_coup <<<dim3(7, B_), 256, 0, stream>>>(cc, cf, sdot, ft, bias, gensig);
    k_scan <<<B_ * 2, 256, 0, stream>>>(gensig, u, iss, ff, out);
}